// Round 10
// baseline (851.366 us; speedup 1.0000x reference)
//
#include <hip/hip_runtime.h>
#include <stdint.h>

// WarpAdjoint: bilinear forward-splat (scatter-add), summed over T.
// R8 post-mortem: flush-atomic theory falsified (no-flush phase1 = 321.8us vs
// 288.8us with flush; time insensitive to 2x occupancy change -> per-CU
// throughput wall INSIDE the splat loop). Phase2 ~160us -> runtime-indexed
// arrays = scratch (rule #20). This round: fix phase2, lean phase1 branches,
// and add a within-probe ablation ladder (loads / +valu / +lds-atomics).

#define BB   8
#define TT   12
#define MM   384
#define NN   384
#define TS   32
#define HALO 8
#define LW   (TS + 2*HALO)      // 48
#define NTX  (NN/TS)            // 12
#define NTY  (MM/TS)            // 12
#define TILES (NTX*NTY)         // 144

// ---------------- Phase 1: splat into LDS tile, then store tile to ws -------
template<bool CPLX, bool USE_WS>
__global__ __launch_bounds__(256)
void splat_phase1(const float* __restrict__ xr, const float* __restrict__ xi,
                  const float* __restrict__ u, float* __restrict__ out,
                  float* __restrict__ ws)
{
    constexpr int ROWW  = CPLX ? (2 * LW + 2) : (LW + 1);
    constexpr int ELEMS = CPLX ? (LW * LW * 2) : (LW * LW);
    __shared__ float tile[LW * ROWW];
    for (int i = threadIdx.x; i < LW * ROWW; i += 256) tile[i] = 0.0f;
    __syncthreads();

    const int blk   = blockIdx.x;            // 0 .. BB*TILES-1
    const int tilei = blk % TILES;
    const int tx    = tilei % NTX;
    const int ty    = tilei / NTX;
    const int b     = blk / TILES;
    const int n0    = tx * TS;
    const int m0    = ty * TS;

    const int lrow = threadIdx.x >> 3;        // 0..31
    const int lc4  = (threadIdx.x & 7) << 2;  // 0,4,...,28
    const int gm   = m0 + lrow;
    const int gn   = n0 + lc4;

    for (int t = 0; t < TT; ++t) {
        const size_t base = ((size_t)((b * TT + t) * MM + gm)) * NN + gn;
        const float4 vr = *reinterpret_cast<const float4*>(xr + base);
        float4 vi = make_float4(0.f, 0.f, 0.f, 0.f);
        if (CPLX) vi = *reinterpret_cast<const float4*>(xi + base);
        const float4 ua = *reinterpret_cast<const float4*>(u + 2 * base);
        const float4 ub = *reinterpret_cast<const float4*>(u + 2 * base + 4);
        const float re[4]  = {vr.x, vr.y, vr.z, vr.w};
        const float im[4]  = {vi.x, vi.y, vi.z, vi.w};
        const float dxs[4] = {ua.x, ua.z, ub.x, ub.z};
        const float dys[4] = {ua.y, ua.w, ub.y, ub.w};
        #pragma unroll
        for (int j = 0; j < 4; ++j) {
            const float fx = (float)(gn + j) + dxs[j];
            const float fy = (float)gm + dys[j];
            const float x0f = floorf(fx);
            const float y0f = floorf(fy);
            const int   x0  = (int)x0f;
            const int   y0  = (int)y0f;
            const float frx = fx - x0f;
            const float fry = fy - y0f;
            const float wx[2] = {1.0f - frx, frx};
            const float wy[2] = {1.0f - fry, fry};
            #pragma unroll
            for (int cy = 0; cy < 2; ++cy) {
                const int yc = y0 + cy;
                const int lr = yc - m0 + HALO;
                #pragma unroll
                for (int cx = 0; cx < 2; ++cx) {
                    const int xc = x0 + cx;
                    const int lc = xc - n0 + HALO;
                    const float w = wx[cx] * wy[cy];
                    // In-halo: no image-validity test needed. Out-of-image
                    // halo cells are never read by phase 2.
                    if ((unsigned)lr < (unsigned)LW && (unsigned)lc < (unsigned)LW) {
                        if (CPLX) {
                            float* p = &tile[lr * ROWW + lc * 2];
                            atomicAdd(p,     w * re[j]);
                            atomicAdd(p + 1, w * im[j]);
                        } else {
                            atomicAdd(&tile[lr * ROWW + lc], w * re[j]);
                        }
                    } else if ((unsigned)yc < (unsigned)MM &&
                               (unsigned)xc < (unsigned)NN) {
                        // out-of-halo (|u|>~8sigma): ~never; direct to out
                        // (runs after memset, before phase2's += read).
                        if (CPLX) {
                            float* q = out + (((size_t)b * MM + yc) * NN + xc) * 2;
                            unsafeAtomicAdd(q,     w * re[j]);
                            unsafeAtomicAdd(q + 1, w * im[j]);
                        } else {
                            unsafeAtomicAdd(out + ((size_t)b * MM + yc) * NN + xc,
                                            w * re[j]);
                        }
                    }
                }
            }
        }
    }
    __syncthreads();

    if (USE_WS) {
        float* dst = ws + (size_t)blk * ELEMS;
        for (int i = threadIdx.x; i < ELEMS; i += 256) {
            if (CPLX) {
                const int pix  = i >> 1;
                const int comp = i & 1;
                dst[i] = tile[(pix / LW) * ROWW + (pix % LW) * 2 + comp];
            } else {
                dst[i] = tile[(i / LW) * ROWW + (i % LW)];
            }
        }
    } else {
        for (int i = threadIdx.x; i < LW * LW; i += 256) {
            const int lr = i / LW;
            const int lc = i - lr * LW;
            const int gy = m0 - HALO + lr;
            const int gx = n0 - HALO + lc;
            if ((unsigned)gy < (unsigned)MM && (unsigned)gx < (unsigned)NN) {
                if (CPLX) {
                    const float vre = tile[lr * ROWW + lc * 2];
                    const float vim = tile[lr * ROWW + lc * 2 + 1];
                    if (vre != 0.0f || vim != 0.0f) {
                        float* q = out + (((size_t)b * MM + gy) * NN + gx) * 2;
                        unsafeAtomicAdd(q,     vre);
                        unsafeAtomicAdd(q + 1, vim);
                    }
                } else {
                    const float v = tile[lr * ROWW + lc];
                    if (v != 0.0f)
                        unsafeAtomicAdd(out + ((size_t)b * MM + gy) * NN + gx, v);
                }
            }
        }
    }
}

// ---------------- Phase 2: gather <=4 covering tiles (NO runtime arrays) ----
template<bool CPLX>
__global__ __launch_bounds__(256)
void splat_phase2(const float* __restrict__ ws, float* __restrict__ out)
{
    constexpr int ELEMS = CPLX ? (LW * LW * 2) : (LW * LW);
    const int idx = blockIdx.x * 256 + threadIdx.x;      // 0 .. BB*MM*NN-1
    const int b   = idx / (MM * NN);
    const int rem = idx - b * (MM * NN);
    const int y   = rem / NN;
    const int x   = rem - y * NN;

    const int ty0 = y >> 5, ry = y & 31;
    const int tx0 = x >> 5, rx = x & 31;
    // second covering tile per axis (at most one; HALO < TS/2)
    const bool eyN = (ry < HALO)       && (ty0 > 0);
    const bool eyS = (ry >= TS - HALO) && (ty0 < NTY - 1);
    const bool ey  = eyN || eyS;
    const int  ty1 = eyN ? ty0 - 1 : ty0 + 1;
    const bool exW = (rx < HALO)       && (tx0 > 0);
    const bool exE = (rx >= TS - HALO) && (tx0 < NTX - 1);
    const bool ex  = exW || exE;
    const int  tx1 = exW ? tx0 - 1 : tx0 + 1;

    float sre = 0.0f, sim = 0.0f;
    #define RD(TY, TX)                                                         \
    {                                                                          \
        const int lr = y - ((TY) * TS - HALO);                                 \
        const int lc = x - ((TX) * TS - HALO);                                 \
        const float* src = ws + ((size_t)(b * TILES + (TY) * NTX + (TX))) * ELEMS; \
        if (CPLX) { sre += src[(lr * LW + lc) * 2];                            \
                    sim += src[(lr * LW + lc) * 2 + 1]; }                      \
        else      { sre += src[lr * LW + lc]; }                                \
    }
    RD(ty0, tx0);
    if (ey)       RD(ty1, tx0);
    if (ex)       RD(ty0, tx1);
    if (ey && ex) RD(ty1, tx1);
    #undef RD

    if (CPLX) {
        out[2 * idx]     += sre;
        out[2 * idx + 1] += sim;
    } else {
        out[idx] += sre;
    }
}

// ---------------- Diagnostics (within-probe ablation ladder) ----------------
// Run AFTER phase2; touch neither out nor live ws. asm sinks prevent DCE.
__global__ __launch_bounds__(256)
void diag_loads(const float* __restrict__ xr, const float* __restrict__ u)
{
    const int blk = blockIdx.x, tilei = blk % TILES;
    const int tx = tilei % NTX, ty = tilei / NTX, b = blk / TILES;
    const int gm = ty * TS + (threadIdx.x >> 3);
    const int gn = tx * TS + ((threadIdx.x & 7) << 2);
    float acc = 0.f;
    for (int t = 0; t < TT; ++t) {
        const size_t base = ((size_t)((b * TT + t) * MM + gm)) * NN + gn;
        const float4 vr = *reinterpret_cast<const float4*>(xr + base);
        const float4 ua = *reinterpret_cast<const float4*>(u + 2 * base);
        const float4 ub = *reinterpret_cast<const float4*>(u + 2 * base + 4);
        acc += vr.x + vr.y + vr.z + vr.w + ua.x + ua.y + ua.z + ua.w
             + ub.x + ub.y + ub.z + ub.w;
    }
    asm volatile("" :: "v"(acc));
}

__global__ __launch_bounds__(256)
void diag_valu(const float* __restrict__ xr, const float* __restrict__ u)
{
    const int blk = blockIdx.x, tilei = blk % TILES;
    const int tx = tilei % NTX, ty = tilei / NTX, b = blk / TILES;
    const int n0 = tx * TS, m0 = ty * TS;
    const int gm = m0 + (threadIdx.x >> 3);
    const int gn = n0 + ((threadIdx.x & 7) << 2);
    float facc = 0.f; int iacc = 0;
    for (int t = 0; t < TT; ++t) {
        const size_t base = ((size_t)((b * TT + t) * MM + gm)) * NN + gn;
        const float4 vr = *reinterpret_cast<const float4*>(xr + base);
        const float4 ua = *reinterpret_cast<const float4*>(u + 2 * base);
        const float4 ub = *reinterpret_cast<const float4*>(u + 2 * base + 4);
        const float re[4]  = {vr.x, vr.y, vr.z, vr.w};
        const float dxs[4] = {ua.x, ua.z, ub.x, ub.z};
        const float dys[4] = {ua.y, ua.w, ub.y, ub.w};
        #pragma unroll
        for (int j = 0; j < 4; ++j) {
            const float fx = (float)(gn + j) + dxs[j];
            const float fy = (float)gm + dys[j];
            const float x0f = floorf(fx), y0f = floorf(fy);
            const int x0 = (int)x0f, y0 = (int)y0f;
            const float frx = fx - x0f, fry = fy - y0f;
            const float wx[2] = {1.f - frx, frx}, wy[2] = {1.f - fry, fry};
            #pragma unroll
            for (int cy = 0; cy < 2; ++cy) {
                const int lr = y0 + cy - m0 + HALO;
                #pragma unroll
                for (int cx = 0; cx < 2; ++cx) {
                    const int lc = x0 + cx - n0 + HALO;
                    facc += wx[cx] * wy[cy] * re[j];
                    iacc ^= lr * (LW + 1) + lc;
                }
            }
        }
    }
    asm volatile("" :: "v"(facc), "v"(iacc));
}

__global__ __launch_bounds__(256)
void diag_atomic(const float* __restrict__ xr, const float* __restrict__ u)
{
    constexpr int ROWW = LW + 1;
    __shared__ float tile[LW * ROWW];
    for (int i = threadIdx.x; i < LW * ROWW; i += 256) tile[i] = 0.0f;
    __syncthreads();
    const int blk = blockIdx.x, tilei = blk % TILES;
    const int tx = tilei % NTX, ty = tilei / NTX, b = blk / TILES;
    const int n0 = tx * TS, m0 = ty * TS;
    const int gm = m0 + (threadIdx.x >> 3);
    const int gn = n0 + ((threadIdx.x & 7) << 2);
    for (int t = 0; t < TT; ++t) {
        const size_t base = ((size_t)((b * TT + t) * MM + gm)) * NN + gn;
        const float4 vr = *reinterpret_cast<const float4*>(xr + base);
        const float4 ua = *reinterpret_cast<const float4*>(u + 2 * base);
        const float4 ub = *reinterpret_cast<const float4*>(u + 2 * base + 4);
        const float re[4]  = {vr.x, vr.y, vr.z, vr.w};
        const float dxs[4] = {ua.x, ua.z, ub.x, ub.z};
        const float dys[4] = {ua.y, ua.w, ub.y, ub.w};
        #pragma unroll
        for (int j = 0; j < 4; ++j) {
            const float fx = (float)(gn + j) + dxs[j];
            const float fy = (float)gm + dys[j];
            const float x0f = floorf(fx), y0f = floorf(fy);
            const int x0 = (int)x0f, y0 = (int)y0f;
            const float frx = fx - x0f, fry = fy - y0f;
            const float wx[2] = {1.f - frx, frx}, wy[2] = {1.f - fry, fry};
            #pragma unroll
            for (int cy = 0; cy < 2; ++cy) {
                const int lr = y0 + cy - m0 + HALO;
                #pragma unroll
                for (int cx = 0; cx < 2; ++cx) {
                    const int lc = x0 + cx - n0 + HALO;
                    // branch-free wrapped address, same statistics as real
                    const int widx = ((lr & 31) + 8) * ROWW + ((lc & 31) + 8);
                    atomicAdd(&tile[widx], wx[cx] * wy[cy] * re[j]);
                }
            }
        }
    }
    __syncthreads();
    asm volatile("" :: "v"(tile[threadIdx.x]));
}

extern "C" void kernel_launch(void* const* d_in, const int* in_sizes, int n_in,
                              void* d_out, int out_size, void* d_ws, size_t ws_size,
                              hipStream_t stream) {
    const float* xr = (const float*)d_in[0];
    const float* xi = (const float*)d_in[1];
    const float* u  = (const float*)d_in[2];
    float* out = (float*)d_out;
    float* ws  = (float*)d_ws;

    hipMemsetAsync(d_out, 0, (size_t)out_size * sizeof(float), stream);

    const bool cplx = (out_size >= 2 * BB * MM * NN);
    const int  grid1 = BB * TILES;                       // 1152
    const int  grid2 = (BB * MM * NN) / 256;             // 4608
    const size_t need = (size_t)grid1 * LW * LW * (cplx ? 2 : 1) * sizeof(float);

    if (ws_size >= need) {
        if (cplx) {
            splat_phase1<true , true ><<<grid1, 256, 0, stream>>>(xr, xi, u, out, ws);
            splat_phase2<true ><<<grid2, 256, 0, stream>>>(ws, out);
        } else {
            splat_phase1<false, true ><<<grid1, 256, 0, stream>>>(xr, xi, u, out, ws);
            splat_phase2<false><<<grid2, 256, 0, stream>>>(ws, out);
        }
    } else {
        if (cplx)
            splat_phase1<true , false><<<grid1, 256, 0, stream>>>(xr, xi, u, out, ws);
        else
            splat_phase1<false, false><<<grid1, 256, 0, stream>>>(xr, xi, u, out, ws);
    }

    // ---- ablation ladder (diagnostics; do not touch out / live ws) ----
    diag_loads <<<grid1, 256, 0, stream>>>(xr, u);
    diag_valu  <<<grid1, 256, 0, stream>>>(xr, u);
    diag_atomic<<<grid1, 256, 0, stream>>>(xr, u);
}